// Round 11
// baseline (622.685 us; speedup 1.0000x reference)
//
#include <hip/hip_runtime.h>
#include <hip/hip_fp16.h>
#include <stdint.h>

#define N_NODES 100000
#define N_EDGES 1600000
#define NB_SCAN 391     // ceil(N_NODES/256)
#define EP_PAD  2000000 // padded-slot capacity (>= E + 3*N = 1.9M)
#define NB_EW   7813    // ceil(EP_PAD/256)

// Round 26. r25 (604us) flat: agg micro-opts exhausted (all <=3%). New model:
// dense phase + W staging dominates the fuse kernels (~50 of ~90us) --
// dense0 (half FLOPs, no agg) = 25us; Wl staged 16KB/block x 6250 blocks =
// 100MB W refetch; 64 ds_read_b32/wave amortized over only 4 nodes.
// Change: 32 nodes/block (4 waves x 8 nodes). Wave runs the PROVEN 16-lane
// agg16p twice, dense with 8 accumulators -> Wl LDS reads per node halve,
// W staging chip-wide halves, block count halves (3125). fuse_heads same.
// Per-node math/order identical -> absmax 0.0625 unchanged.

__device__ __forceinline__ float bf2f(unsigned short s) {
    return __uint_as_float(((unsigned)s) << 16);
}
__device__ __forceinline__ unsigned short f2bf(float f) {
    unsigned u = __float_as_uint(f);
    u += 0x7fffu + ((u >> 16) & 1u);
    return (unsigned short)(u >> 16);
}
__device__ __forceinline__ unsigned short f2h(float f) {
    __half h = __float2half(f);
    return __builtin_bit_cast(unsigned short, h);
}
template <bool BF16>
__device__ __forceinline__ float LD(const void* p, size_t i) {
    if (BF16) return bf2f(((const unsigned short*)p)[i]);
    return ((const float*)p)[i];
}
__device__ __forceinline__ int pad4(int d) { return (d + 3) & ~3; }

// ---------------- dtype detection (proven) ----------------
__global__ void k_detect(const unsigned* __restrict__ xw, int* __restrict__ flag) {
    __shared__ int tot;
    if (threadIdx.x == 0) tot = 0;
    __syncthreads();
    int hit = 0;
    for (int i = threadIdx.x; i < 1024; i += 256) {
        unsigned e = (xw[i] >> 7) & 0xFFu;
        if (e >= 110u && e <= 135u) hit++;
    }
    atomicAdd(&tot, hit);
    __syncthreads();
    if (threadIdx.x == 0) *flag = (tot >= 512) ? 1 : 0;
}

// ---------------- CSR build (scans over PADDED degrees) ----------------

__global__ void k_hist(const int* __restrict__ ei, int* __restrict__ deg) {
    int e = blockIdx.x * 256 + threadIdx.x;
    if (e < N_EDGES) atomicAdd(&deg[ei[N_EDGES + e]], 1);
}

__global__ void k_scan_partial(const int* __restrict__ deg, int* __restrict__ bsum) {
    int t = threadIdx.x;
    int i = blockIdx.x * 256 + t;
    int v = (i < N_NODES) ? pad4(deg[i]) : 0;
    for (int off = 32; off > 0; off >>= 1) v += __shfl_down(v, off, 64);
    __shared__ int ws4[4];
    if ((t & 63) == 0) ws4[t >> 6] = v;
    __syncthreads();
    if (t == 0) bsum[blockIdx.x] = ws4[0] + ws4[1] + ws4[2] + ws4[3];
}

__global__ void k_scan_mid(const int* __restrict__ bsum, int* __restrict__ boff) {
    __shared__ int s[512];
    int t = threadIdx.x;
    int v = (t < NB_SCAN) ? bsum[t] : 0;
    s[t] = v;
    __syncthreads();
    for (int off = 1; off < 512; off <<= 1) {
        int x = (t >= off) ? s[t - off] : 0;
        __syncthreads();
        s[t] += x;
        __syncthreads();
    }
    if (t < NB_SCAN) boff[t] = s[t] - v;   // exclusive
}

__global__ void k_scan_final(const int* __restrict__ deg, const int* __restrict__ boff,
                             int* __restrict__ row_start, int* __restrict__ cursor) {
    __shared__ int s[256];
    int t = threadIdx.x;
    int i = blockIdx.x * 256 + t;
    int v = (i < N_NODES) ? pad4(deg[i]) : 0;
    s[t] = v;
    __syncthreads();
    for (int off = 1; off < 256; off <<= 1) {
        int x = (t >= off) ? s[t - off] : 0;
        __syncthreads();
        s[t] += x;
        __syncthreads();
    }
    if (i < N_NODES) {
        int rs = boff[blockIdx.x] + s[t] - v;
        row_start[i] = rs;
        cursor[i] = rs;
    }
}

// ---------------- CSR scatter: 1 edge/thread (proven best) ----------------

__device__ void scatter_bf(const int* __restrict__ ei, const unsigned short* __restrict__ ea,
                           int* __restrict__ cursor, uint2* __restrict__ rec8) {
    int e = blockIdx.x * 256 + threadIdx.x;   // grid exact: 6250*256 = 1.6M
    int s = ei[e];
    int d = ei[N_EDGES + e];
    unsigned a0 = ea[(size_t)e * 2];
    unsigned a1 = ea[(size_t)e * 2 + 1];
    int slot = atomicAdd(&cursor[d], 1);
    rec8[slot] = make_uint2((unsigned)s, a0 | (a1 << 16));
}

__device__ void scatter_fp(const int* __restrict__ ei, const float* __restrict__ ea,
                           int* __restrict__ cursor, uint4* __restrict__ rec16) {
    int e = blockIdx.x * 256 + threadIdx.x;
    int s = ei[e];
    int d = ei[N_EDGES + e];
    float a0 = ea[(size_t)e * 2];
    float a1 = ea[(size_t)e * 2 + 1];
    int slot = atomicAdd(&cursor[d], 1);
    rec16[slot] = make_uint4((unsigned)s, __float_as_uint(a0), __float_as_uint(a1), 0u);
}

__global__ void k_scatter(const int* __restrict__ flag, const int* ei, const void* ea,
                          int* cursor, void* staging) {
    if (*flag) scatter_bf(ei, (const unsigned short*)ea, cursor, (uint2*)staging);
    else       scatter_fp(ei, (const float*)ea, cursor, (uint4*)staging);
}

// ---------------- edge-MLP pass: slot-ordered, fully coalesced ----------------

template <bool BF>
__device__ __forceinline__ void ew_body(const void* __restrict__ staging,
                                        const void* ew1, const void* eb1,
                                        const void* ew2, const void* eb2,
                                        int* __restrict__ csr_off,
                                        float* __restrict__ ew4,
                                        float (*w1)[2][16], float (*b1)[16],
                                        float (*w2)[16], float* b2) {
    int t = threadIdx.x;
    if (t < 128) ((float*)w1)[t] = LD<BF>(ew1, t);
    else if (t < 192) ((float*)b1)[t - 128] = LD<BF>(eb1, t - 128);
    else ((float*)w2)[t - 192] = LD<BF>(ew2, t - 192);
    if (t < 4) b2[t] = LD<BF>(eb2, t);
    __syncthreads();

    int e = blockIdx.x * 256 + t;
    if (e >= EP_PAD) return;
    float a0, a1;
    unsigned src;
    if (BF) {
        uint2 u = ((const uint2*)staging)[e];
        src = u.x;
        a0 = bf2f((unsigned short)(u.y & 0xffffu));
        a1 = bf2f((unsigned short)(u.y >> 16));
    } else {
        uint4 u = ((const uint4*)staging)[e];
        src = u.x;
        a0 = __uint_as_float(u.y);
        a1 = __uint_as_float(u.z);
    }
    if (src == 0xFFFFFFFFu) {   // pad / unused slot
        csr_off[e] = 0;
        #pragma unroll
        for (int l = 0; l < 4; l++) ew4[(size_t)l * EP_PAD + e] = 0.f;
        return;
    }
    csr_off[e] = (int)(src * 128u);
    #pragma unroll
    for (int l = 0; l < 4; l++) {
        float z = b2[l];
        #pragma unroll
        for (int q = 0; q < 16; q++) {
            float hj = fmaf(a0, w1[l][0][q], fmaf(a1, w1[l][1][q], b1[l][q]));
            z = fmaf(fmaxf(hj, 0.f), w2[l][q], z);
        }
        ew4[(size_t)l * EP_PAD + e] = 1.f / (1.f + expf(-z));
    }
}

__global__ void k_ew(const int* __restrict__ flag, const void* __restrict__ staging,
                     const void* ew1, const void* eb1, const void* ew2, const void* eb2,
                     int* csr_off, float* ew4) {
    __shared__ float w1[4][2][16], b1[4][16], w2[4][16], b2[4];
    if (*flag) ew_body<true>(staging, ew1, eb1, ew2, eb2, csr_off, ew4, w1, b1, w2, b2);
    else       ew_body<false>(staging, ew1, eb1, ew2, eb2, csr_off, ew4, w1, b1, w2, b2);
}

// ---------------- layer 0 dense (h stored as f16) ----------------

template <bool BF>
__device__ __forceinline__ void dense0_body(const void* __restrict__ x,
                                            const void* __restrict__ W,
                                            const void* __restrict__ b,
                                            unsigned short* __restrict__ h,
                                            float* Wl, float (*xl)[32]) {
    int t = threadIdx.x, w = t >> 6, lane = t & 63;
    for (int i = t; i < 32 * 64; i += 256) Wl[i] = LD<BF>(W, i);
    int v0 = blockIdx.x * 16 + w * 4;
    if (lane < 32) {
        #pragma unroll
        for (int n = 0; n < 4; n++)
            xl[w * 4 + n][lane] = LD<BF>(x, (size_t)(v0 + n) * 32 + lane);
    }
    __syncthreads();
    float bias = LD<BF>(b, lane);
    float a0 = bias, a1 = bias, a2 = bias, a3 = bias;
    #pragma unroll 8
    for (int k = 0; k < 32; k++) {
        float wv = Wl[k * 64 + lane];
        a0 = fmaf(xl[w * 4 + 0][k], wv, a0);
        a1 = fmaf(xl[w * 4 + 1][k], wv, a1);
        a2 = fmaf(xl[w * 4 + 2][k], wv, a2);
        a3 = fmaf(xl[w * 4 + 3][k], wv, a3);
    }
    h[(size_t)(v0 + 0) * 64 + lane] = f2h(a0);
    h[(size_t)(v0 + 1) * 64 + lane] = f2h(a1);
    h[(size_t)(v0 + 2) * 64 + lane] = f2h(a2);
    h[(size_t)(v0 + 3) * 64 + lane] = f2h(a3);
}

__global__ void k_dense0(const int* __restrict__ flag, const void* x, const void* W,
                         const void* b, unsigned short* h) {
    __shared__ float Wl[32 * 64];
    __shared__ float xl[16][32];
    if (*flag) dense0_body<true>(x, W, b, h, Wl, xl);
    else       dense0_body<false>(x, W, b, h, Wl, xl);
}

// ---------------- aggregation: 16 lanes/node, branchless 4-edge, f16 h ------
// (proven r25 loop, unchanged)

__device__ __forceinline__ float4 agg16p(int p, int rem,
                                         const int* __restrict__ csr_off,
                                         const float* __restrict__ ew,
                                         const char* __restrict__ hb,
                                         int j8) {
    float a0 = 0.f, a1 = 0.f, a2 = 0.f, a3 = 0.f;
    if (rem > 0) {
        int o0 = csr_off[p], o1 = csr_off[p + 1], o2 = csr_off[p + 2], o3 = csr_off[p + 3];
        float e0 = ew[p], e1 = ew[p + 1], e2 = ew[p + 2], e3 = ew[p + 3];
        while (rem > 0) {
            int n0 = csr_off[p + 4], n1 = csr_off[p + 5];
            int n2 = csr_off[p + 6], n3 = csr_off[p + 7];
            float f0 = ew[p + 4], f1 = ew[p + 5], f2 = ew[p + 6], f3 = ew[p + 7];
            uint2 g0 = *(const uint2*)(hb + (unsigned)(o0 + j8));
            uint2 g1 = *(const uint2*)(hb + (unsigned)(o1 + j8));
            uint2 g2 = *(const uint2*)(hb + (unsigned)(o2 + j8));
            uint2 g3 = *(const uint2*)(hb + (unsigned)(o3 + j8));
            __half2 h0x = __builtin_bit_cast(__half2, g0.x);
            __half2 h0y = __builtin_bit_cast(__half2, g0.y);
            __half2 h1x = __builtin_bit_cast(__half2, g1.x);
            __half2 h1y = __builtin_bit_cast(__half2, g1.y);
            __half2 h2x = __builtin_bit_cast(__half2, g2.x);
            __half2 h2y = __builtin_bit_cast(__half2, g2.y);
            __half2 h3x = __builtin_bit_cast(__half2, g3.x);
            __half2 h3y = __builtin_bit_cast(__half2, g3.y);
            a0 = fmaf(e0, __low2float(h0x), a0);
            a1 = fmaf(e0, __high2float(h0x), a1);
            a2 = fmaf(e0, __low2float(h0y), a2);
            a3 = fmaf(e0, __high2float(h0y), a3);
            a0 = fmaf(e1, __low2float(h1x), a0);
            a1 = fmaf(e1, __high2float(h1x), a1);
            a2 = fmaf(e1, __low2float(h1y), a2);
            a3 = fmaf(e1, __high2float(h1y), a3);
            a0 = fmaf(e2, __low2float(h2x), a0);
            a1 = fmaf(e2, __high2float(h2x), a1);
            a2 = fmaf(e2, __low2float(h2y), a2);
            a3 = fmaf(e2, __high2float(h2y), a3);
            a0 = fmaf(e3, __low2float(h3x), a0);
            a1 = fmaf(e3, __high2float(h3x), a1);
            a2 = fmaf(e3, __low2float(h3y), a2);
            a3 = fmaf(e3, __high2float(h3y), a3);
            o0 = n0; e0 = f0; o1 = n1; e1 = f1;
            o2 = n2; e2 = f2; o3 = n3; e3 = f3;
            p += 4; rem -= 4;
        }
    }
    return make_float4(fmaxf(a0, 0.f), fmaxf(a1, 0.f), fmaxf(a2, 0.f), fmaxf(a3, 0.f));
}

// ---------------- fused: x = relu(agg(h_in)); h_out = x @ W + b ----------------
// 32 nodes/block (4 waves x 8 nodes); agg runs twice per wave (4 nodes each);
// dense with 8 accumulators -> Wl LDS reads per node halved. LDS 24KB.

template <bool BF>
__device__ __forceinline__ void fuse_body(const int* row_start, const int* deg,
                                          const int* __restrict__ csr_off,
                                          const float* __restrict__ ew,
                                          const char* __restrict__ hb,
                                          const void* W, int Woff, const void* b, int boff,
                                          unsigned short* h_out,
                                          float* Wl, float (*xs)[64]) {
    int t = threadIdx.x, w = t >> 6, lane = t & 63;
    for (int i = t; i < 64 * 64; i += 256) Wl[i] = LD<BF>(W, Woff + i);

    int g = lane >> 4, j = lane & 15;
    int base = blockIdx.x * 32 + w * 8;   // grid exact: 3125*32 = 100000
    {
        int v = base + g;
        float4 r = agg16p(row_start[v], pad4(deg[v]), csr_off, ew, hb, j * 8);
        *(float4*)&xs[w * 8 + g][4 * j] = r;
    }
    {
        int v = base + 4 + g;
        float4 r = agg16p(row_start[v], pad4(deg[v]), csr_off, ew, hb, j * 8);
        *(float4*)&xs[w * 8 + 4 + g][4 * j] = r;
    }
    __syncthreads();

    float bias = LD<BF>(b, boff + lane);
    float A0 = bias, A1 = bias, A2 = bias, A3 = bias;
    float A4 = bias, A5 = bias, A6 = bias, A7 = bias;
    for (int k = 0; k < 64; k += 4) {
        float w0 = Wl[(k + 0) * 64 + lane];
        float w1 = Wl[(k + 1) * 64 + lane];
        float w2 = Wl[(k + 2) * 64 + lane];
        float w3 = Wl[(k + 3) * 64 + lane];
        float4 x0 = *(const float4*)&xs[w * 8 + 0][k];   // lane-uniform: LDS broadcast
        float4 x1 = *(const float4*)&xs[w * 8 + 1][k];
        float4 x2 = *(const float4*)&xs[w * 8 + 2][k];
        float4 x3 = *(const float4*)&xs[w * 8 + 3][k];
        A0 = fmaf(x0.x, w0, A0); A0 = fmaf(x0.y, w1, A0); A0 = fmaf(x0.z, w2, A0); A0 = fmaf(x0.w, w3, A0);
        A1 = fmaf(x1.x, w0, A1); A1 = fmaf(x1.y, w1, A1); A1 = fmaf(x1.z, w2, A1); A1 = fmaf(x1.w, w3, A1);
        A2 = fmaf(x2.x, w0, A2); A2 = fmaf(x2.y, w1, A2); A2 = fmaf(x2.z, w2, A2); A2 = fmaf(x2.w, w3, A2);
        A3 = fmaf(x3.x, w0, A3); A3 = fmaf(x3.y, w1, A3); A3 = fmaf(x3.z, w2, A3); A3 = fmaf(x3.w, w3, A3);
        float4 x4 = *(const float4*)&xs[w * 8 + 4][k];
        float4 x5 = *(const float4*)&xs[w * 8 + 5][k];
        float4 x6 = *(const float4*)&xs[w * 8 + 6][k];
        float4 x7 = *(const float4*)&xs[w * 8 + 7][k];
        A4 = fmaf(x4.x, w0, A4); A4 = fmaf(x4.y, w1, A4); A4 = fmaf(x4.z, w2, A4); A4 = fmaf(x4.w, w3, A4);
        A5 = fmaf(x5.x, w0, A5); A5 = fmaf(x5.y, w1, A5); A5 = fmaf(x5.z, w2, A5); A5 = fmaf(x5.w, w3, A5);
        A6 = fmaf(x6.x, w0, A6); A6 = fmaf(x6.y, w1, A6); A6 = fmaf(x6.z, w2, A6); A6 = fmaf(x6.w, w3, A6);
        A7 = fmaf(x7.x, w0, A7); A7 = fmaf(x7.y, w1, A7); A7 = fmaf(x7.z, w2, A7); A7 = fmaf(x7.w, w3, A7);
    }
    h_out[(size_t)(base + 0) * 64 + lane] = f2h(A0);
    h_out[(size_t)(base + 1) * 64 + lane] = f2h(A1);
    h_out[(size_t)(base + 2) * 64 + lane] = f2h(A2);
    h_out[(size_t)(base + 3) * 64 + lane] = f2h(A3);
    h_out[(size_t)(base + 4) * 64 + lane] = f2h(A4);
    h_out[(size_t)(base + 5) * 64 + lane] = f2h(A5);
    h_out[(size_t)(base + 6) * 64 + lane] = f2h(A6);
    h_out[(size_t)(base + 7) * 64 + lane] = f2h(A7);
}

__global__ void k_fuse(const int* __restrict__ flag,
                       const int* row_start, const int* deg,
                       const int* __restrict__ csr_off, const float* __restrict__ ew,
                       const void* hu,
                       const void* W, int Woff, const void* b, int boff,
                       unsigned short* h_out) {
    __shared__ float Wl[64 * 64];
    __shared__ float xs[32][64];
    if (*flag)
        fuse_body<true>(row_start, deg, csr_off, ew, (const char*)hu,
                        W, Woff, b, boff, h_out, Wl, xs);
    else
        fuse_body<false>(row_start, deg, csr_off, ew, (const char*)hu,
                         W, Woff, b, boff, h_out, Wl, xs);
}

// ---------------- fused final: x3 = relu(agg(h3)); heads -> out ---------------
// 32 nodes/block (4 waves x 8 nodes); LDS ~37KB

template <bool BF>
__device__ __forceinline__ void fuse_heads_body(
        const int* row_start, const int* deg,
        const int* __restrict__ csr_off, const float* __restrict__ ew,
        const char* __restrict__ hb,
        const void* rh1w, const void* rh1b, const void* rh2w, const void* rh2b,
        const void* meanw, const void* meanb, const void* stdw, const void* stdb,
        const void* cls1w, const void* cls1b, const void* cls2w, const void* cls2b,
        void* __restrict__ out,
        float* s_rh1, float* s_cls1, float* s_rh2, float* s_cls2,
        float* s_rh1b, float* s_cls1b, float* s_rh2b, float* s_mw, float* s_sw,
        float* s_c2b, float* s_msb,
        float (*xs)[64], float (*r1)[32], float (*c1h)[32], float (*r2)[16]) {
    int t = threadIdx.x, w = t >> 6, lane = t & 63;
    for (int i = t; i < 2048; i += 256) { s_rh1[i] = LD<BF>(rh1w, i); s_cls1[i] = LD<BF>(cls1w, i); }
    for (int i = t; i < 512; i += 256) s_rh2[i] = LD<BF>(rh2w, i);
    if (t < 64) s_cls2[t] = LD<BF>(cls2w, t);
    if (t < 32) { s_rh1b[t] = LD<BF>(rh1b, t); s_cls1b[t] = LD<BF>(cls1b, t); }
    else if (t < 48) { int i = t - 32; s_rh2b[i] = LD<BF>(rh2b, i); s_mw[i] = LD<BF>(meanw, i); s_sw[i] = LD<BF>(stdw, i); }
    else if (t == 48) { s_msb[0] = LD<BF>(meanb, 0); s_msb[1] = LD<BF>(stdb, 0); }
    else if (t == 49) { s_c2b[0] = LD<BF>(cls2b, 0); s_c2b[1] = LD<BF>(cls2b, 1); }

    int g = lane >> 4, j = lane & 15;
    int base = blockIdx.x * 32 + w * 8;   // grid exact: 3125*32 = 100000
    {
        int v = base + g;
        float4 r = agg16p(row_start[v], pad4(deg[v]), csr_off, ew, hb, j * 8);
        *(float4*)&xs[w * 8 + g][4 * j] = r;
    }
    {
        int v = base + 4 + g;
        float4 r = agg16p(row_start[v], pad4(deg[v]), csr_off, ew, hb, j * 8);
        *(float4*)&xs[w * 8 + 4 + g][4 * j] = r;
    }
    __syncthreads();

    #pragma unroll
    for (int n = 0; n < 8; n++) {
        int idx = w * 8 + n;
        int c = lane & 31;
        const float* Wp = (lane < 32) ? s_rh1 : s_cls1;
        float a = (lane < 32) ? s_rh1b[c] : s_cls1b[c];
        #pragma unroll 8
        for (int k = 0; k < 64; k++) a = fmaf(xs[idx][k], Wp[k * 32 + c], a);
        a = fmaxf(a, 0.f);
        if (lane < 32) r1[idx][c] = a; else c1h[idx][c] = a;
    }
    __syncthreads();

    #pragma unroll
    for (int n = 0; n < 8; n++) {
        int idx = w * 8 + n;
        if (lane < 16) {
            float a = s_rh2b[lane];
            #pragma unroll
            for (int k = 0; k < 32; k++) a = fmaf(r1[idx][k], s_rh2[k * 16 + lane], a);
            r2[idx][lane] = fmaxf(a, 0.f);
        }
    }
    __syncthreads();

    #pragma unroll
    for (int n = 0; n < 8; n++) {
        int idx = w * 8 + n;
        int v = base + n;
        if (lane == 0) {
            float m = s_msb[0];
            #pragma unroll
            for (int k = 0; k < 16; k++) m = fmaf(r2[idx][k], s_mw[k], m);
            if (BF) ((unsigned short*)out)[v] = f2bf(m); else ((float*)out)[v] = m;
        } else if (lane == 1) {
            float sv = s_msb[1];
            #pragma unroll
            for (int k = 0; k < 16; k++) sv = fmaf(r2[idx][k], s_sw[k], sv);
            float sp = fmaxf(sv, 0.f) + log1pf(expf(-fabsf(sv)));   // stable softplus
            if (BF) ((unsigned short*)out)[N_NODES + v] = f2bf(sp); else ((float*)out)[N_NODES + v] = sp;
        } else if (lane < 4) {
            int jj = lane - 2;
            float a = s_c2b[jj];
            #pragma unroll
            for (int k = 0; k < 32; k++) a = fmaf(c1h[idx][k], s_cls2[k * 2 + jj], a);
            size_t pos = (size_t)2 * N_NODES + (size_t)v * 2 + jj;
            if (BF) ((unsigned short*)out)[pos] = f2bf(a); else ((float*)out)[pos] = a;
        }
    }
}

__global__ void k_fuse_heads(const int* __restrict__ flag,
                             const int* row_start, const int* deg,
                             const int* __restrict__ csr_off, const float* __restrict__ ew,
                             const void* hu,
                             const void* rh1w, const void* rh1b, const void* rh2w, const void* rh2b,
                             const void* meanw, const void* meanb, const void* stdw, const void* stdb,
                             const void* cls1w, const void* cls1b, const void* cls2w, const void* cls2b,
                             void* out) {
    __shared__ float s_rh1[64 * 32], s_cls1[64 * 32], s_rh2[32 * 16], s_cls2[32 * 2];
    __shared__ float s_rh1b[32], s_cls1b[32], s_rh2b[16], s_mw[16], s_sw[16], s_c2b[2], s_msb[2];
    __shared__ float xs[32][64], r1[32][32], c1h[32][32], r2[32][16];
    if (*flag)
        fuse_heads_body<true>(row_start, deg, csr_off, ew, (const char*)hu,
                              rh1w, rh1b, rh2w, rh2b, meanw, meanb, stdw, stdb,
                              cls1w, cls1b, cls2w, cls2b, out,
                              s_rh1, s_cls1, s_rh2, s_cls2, s_rh1b, s_cls1b, s_rh2b,
                              s_mw, s_sw, s_c2b, s_msb, xs, r1, c1h, r2);
    else
        fuse_heads_body<false>(row_start, deg, csr_off, ew, (const char*)hu,
                               rh1w, rh1b, rh2w, rh2b, meanw, meanb, stdw, stdb,
                               cls1w, cls1b, cls2w, cls2b, out,
                               s_rh1, s_cls1, s_rh2, s_cls2, s_rh1b, s_cls1b, s_rh2b,
                               s_mw, s_sw, s_c2b, s_msb, xs, r1, c1h, r2);
}

// ---------------- launch ----------------

extern "C" void kernel_launch(void* const* d_in, const int* in_sizes, int n_in,
                              void* d_out, int out_size, void* d_ws, size_t ws_size,
                              hipStream_t stream) {
    const void* x_in  = d_in[0];
    const int* ei     = (const int*)d_in[1];
    const void* ea    = d_in[2];
    const void* W0    = d_in[3];
    const void* b0    = d_in[4];
    const void* Ws    = d_in[5];
    const void* bs    = d_in[6];
    const void* ew1   = d_in[7];
    const void* eb1   = d_in[8];
    const void* ew2   = d_in[9];
    const void* eb2   = d_in[10];
    const void* rh1w  = d_in[11];
    const void* rh1b  = d_in[12];
    const void* rh2w  = d_in[13];
    const void* rh2b  = d_in[14];
    const void* meanw = d_in[15];
    const void* meanb = d_in[16];
    const void* stdw  = d_in[17];
    const void* stdb  = d_in[18];
    const void* cls1w = d_in[19];
    const void* cls1b = d_in[20];
    const void* cls2w = d_in[21];
    const void* cls2b = d_in[22];

    char* wsp = (char*)d_ws;
    auto alloc = [&](size_t bytes) -> char* {
        char* p = wsp;
        wsp += (bytes + 255) & ~(size_t)255;
        return p;
    };
    // footprint: misc ~1.3 + csr_off 8 + ew4 32 + union 32 = ~73.3 MB (< 78.2)
    int* flag       = (int*)alloc(4);
    int* deg        = (int*)alloc((size_t)N_NODES * 4);
    int* row_start  = (int*)alloc((size_t)N_NODES * 4);
    int* cursor     = (int*)alloc((size_t)N_NODES * 4);
    int* bsum       = (int*)alloc((size_t)NB_SCAN * 4);
    int* boff       = (int*)alloc((size_t)NB_SCAN * 4);
    int* csr_off    = (int*)alloc((size_t)EP_PAD * 4);
    float* ew4      = (float*)alloc((size_t)4 * EP_PAD * 4);
    char* hreg      = alloc((size_t)EP_PAD * 16);        // union region, 32 MB
    void* staging   = (void*)hreg;
    unsigned short* hA = (unsigned short*)hreg;
    unsigned short* hB = (unsigned short*)(hreg + (size_t)N_NODES * 64 * 2);

    k_detect<<<1, 256, 0, stream>>>((const unsigned*)x_in, flag);
    hipMemsetAsync(deg, 0, (size_t)N_NODES * 4, stream);
    hipMemsetAsync(staging, 0xFF, (size_t)EP_PAD * 16, stream);  // sentinel for pad slots
    k_hist<<<6250, 256, 0, stream>>>(ei, deg);
    k_scan_partial<<<NB_SCAN, 256, 0, stream>>>(deg, bsum);
    k_scan_mid<<<1, 512, 0, stream>>>(bsum, boff);
    k_scan_final<<<NB_SCAN, 256, 0, stream>>>(deg, boff, row_start, cursor);
    k_scatter<<<6250, 256, 0, stream>>>(flag, ei, ea, cursor, staging);
    k_ew<<<NB_EW, 256, 0, stream>>>(flag, staging, ew1, eb1, ew2, eb2, csr_off, ew4);

    // h0 = x_in @ W0 + b0   (hA clobbers staging region -- dead after k_ew)
    k_dense0<<<6250, 256, 0, stream>>>(flag, x_in, W0, b0, hA);

    unsigned short* hin = hA;
    unsigned short* hout = hB;
    for (int l = 0; l < 3; l++) {
        k_fuse<<<3125, 256, 0, stream>>>(flag, row_start, deg, csr_off,
                                         ew4 + (size_t)l * EP_PAD, hin,
                                         Ws, l * 64 * 64, bs, l * 64, hout);
        unsigned short* tmp = hin; hin = hout; hout = tmp;
    }
    k_fuse_heads<<<3125, 256, 0, stream>>>(flag, row_start, deg, csr_off,
                                           ew4 + (size_t)3 * EP_PAD, hin,
                                           rh1w, rh1b, rh2w, rh2b, meanw, meanb,
                                           stdw, stdb, cls1w, cls1b, cls2w, cls2b,
                                           d_out);
}

// Round 12
// 595.446 us; speedup vs baseline: 1.0457x; 1.0457x over previous
//
#include <hip/hip_runtime.h>
#include <stdint.h>

#define N_NODES 100000
#define N_EDGES 1600000
#define NB_SCAN 391   // ceil(N_NODES/256)

// Round 27 (final): revert to the best-measured configuration (r19/r21,
// 596us, reproduced twice). r26 post-mortem: 32-node blocks grew LDS to
// 37.9KB -> occupancy 48->36% -> latency-bound agg lost wave-level latency
// hiding; regression. Eleven rounds bracket the floors:
//  - k_scatter ~110us: WRITE pinned 101MB = 200K lines x 8 XCD dirty
//    replication (plain/nt/8B/16B/1-or-4-edge all identical). Memory floor.
//  - fuse kernels: 81MB irreducible random h-row gather (12.8MB table >>
//    4MB/XCD L2, random graph) at ~790GB/s + VALUBusy 63% -- co-saturated.
//  - agg micro-opts (width/unroll/dtype/pad/sort/nodes-per-block) all <=3%.
// This source = r19 verbatim: 16 nodes/block, 16-lane/node agg with scalar
// per-lane accumulators, 2-edge depth-1 pipeline, bf16 h, 16B staging.

__device__ __forceinline__ float bf2f(unsigned short s) {
    return __uint_as_float(((unsigned)s) << 16);
}
__device__ __forceinline__ unsigned short f2bf(float f) {
    unsigned u = __float_as_uint(f);
    u += 0x7fffu + ((u >> 16) & 1u);
    return (unsigned short)(u >> 16);
}
template <bool BF16>
__device__ __forceinline__ float LD(const void* p, size_t i) {
    if (BF16) return bf2f(((const unsigned short*)p)[i]);
    return ((const float*)p)[i];
}

// ---------------- dtype detection (proven) ----------------
__global__ void k_detect(const unsigned* __restrict__ xw, int* __restrict__ flag) {
    __shared__ int tot;
    if (threadIdx.x == 0) tot = 0;
    __syncthreads();
    int hit = 0;
    for (int i = threadIdx.x; i < 1024; i += 256) {
        unsigned e = (xw[i] >> 7) & 0xFFu;
        if (e >= 110u && e <= 135u) hit++;
    }
    atomicAdd(&tot, hit);
    __syncthreads();
    if (threadIdx.x == 0) *flag = (tot >= 512) ? 1 : 0;
}

// ---------------- CSR build ----------------

__global__ void k_hist(const int* __restrict__ ei, int* __restrict__ deg) {
    int e = blockIdx.x * 256 + threadIdx.x;
    if (e < N_EDGES) atomicAdd(&deg[ei[N_EDGES + e]], 1);
}

__global__ void k_scan_partial(const int* __restrict__ deg, int* __restrict__ bsum) {
    int t = threadIdx.x;
    int i = blockIdx.x * 256 + t;
    int v = (i < N_NODES) ? deg[i] : 0;
    for (int off = 32; off > 0; off >>= 1) v += __shfl_down(v, off, 64);
    __shared__ int ws4[4];
    if ((t & 63) == 0) ws4[t >> 6] = v;
    __syncthreads();
    if (t == 0) bsum[blockIdx.x] = ws4[0] + ws4[1] + ws4[2] + ws4[3];
}

__global__ void k_scan_mid(const int* __restrict__ bsum, int* __restrict__ boff) {
    __shared__ int s[512];
    int t = threadIdx.x;
    int v = (t < NB_SCAN) ? bsum[t] : 0;
    s[t] = v;
    __syncthreads();
    for (int off = 1; off < 512; off <<= 1) {
        int x = (t >= off) ? s[t - off] : 0;
        __syncthreads();
        s[t] += x;
        __syncthreads();
    }
    if (t < NB_SCAN) boff[t] = s[t] - v;   // exclusive
}

__global__ void k_scan_final(const int* __restrict__ deg, const int* __restrict__ boff,
                             int* __restrict__ row_start, int* __restrict__ cursor) {
    __shared__ int s[256];
    int t = threadIdx.x;
    int i = blockIdx.x * 256 + t;
    int v = (i < N_NODES) ? deg[i] : 0;
    s[t] = v;
    __syncthreads();
    for (int off = 1; off < 256; off <<= 1) {
        int x = (t >= off) ? s[t - off] : 0;
        __syncthreads();
        s[t] += x;
        __syncthreads();
    }
    if (i < N_NODES) {
        int rs = boff[blockIdx.x] + s[t] - v;
        row_start[i] = rs;
        cursor[i] = rs;
    }
}

// ---------------- CSR scatter: ONE 16B packed write per edge ----------------

template <bool BF>
__device__ __forceinline__ void scatter_body(const int* __restrict__ ei,
                                             const void* __restrict__ ea,
                                             int* __restrict__ cursor,
                                             uint4* __restrict__ csr_edge) {
    int e = blockIdx.x * 256 + threadIdx.x;   // grid exact: 6250*256 = 1.6M
    int s = ei[e];
    int d = ei[N_EDGES + e];
    float a0 = LD<BF>(ea, (size_t)e * 2);
    float a1 = LD<BF>(ea, (size_t)e * 2 + 1);
    int slot = atomicAdd(&cursor[d], 1);
    csr_edge[slot] = make_uint4((unsigned)s, __float_as_uint(a0), __float_as_uint(a1), 0u);
}

__global__ void k_scatter(const int* __restrict__ flag, const int* ei, const void* ea,
                          int* cursor, uint4* csr_edge) {
    if (*flag) scatter_body<true>(ei, ea, cursor, csr_edge);
    else       scatter_body<false>(ei, ea, cursor, csr_edge);
}

// ---------------- edge-MLP pass: slot-ordered, fully coalesced ----------------

template <bool BF>
__device__ __forceinline__ void ew_body(const uint4* __restrict__ csr_edge,
                                        const void* ew1, const void* eb1,
                                        const void* ew2, const void* eb2,
                                        int* __restrict__ csr_src,
                                        float* __restrict__ ew4,
                                        float (*w1)[2][16], float (*b1)[16],
                                        float (*w2)[16], float* b2) {
    int t = threadIdx.x;
    if (t < 128) ((float*)w1)[t] = LD<BF>(ew1, t);
    else if (t < 192) ((float*)b1)[t - 128] = LD<BF>(eb1, t - 128);
    else ((float*)w2)[t - 192] = LD<BF>(ew2, t - 192);
    if (t < 4) b2[t] = LD<BF>(eb2, t);
    __syncthreads();

    int e = blockIdx.x * 256 + t;   // grid exact: 6250*256 = 1.6M
    uint4 u = csr_edge[e];
    csr_src[e] = (int)u.x;
    float a0 = __uint_as_float(u.y);
    float a1 = __uint_as_float(u.z);
    #pragma unroll
    for (int l = 0; l < 4; l++) {
        float z = b2[l];
        #pragma unroll
        for (int q = 0; q < 16; q++) {
            float hj = fmaf(a0, w1[l][0][q], fmaf(a1, w1[l][1][q], b1[l][q]));
            z = fmaf(fmaxf(hj, 0.f), w2[l][q], z);
        }
        ew4[(size_t)l * N_EDGES + e] = 1.f / (1.f + expf(-z));
    }
}

__global__ void k_ew(const int* __restrict__ flag, const uint4* __restrict__ csr_edge,
                     const void* ew1, const void* eb1, const void* ew2, const void* eb2,
                     int* csr_src, float* ew4) {
    __shared__ float w1[4][2][16], b1[4][16], w2[4][16], b2[4];
    if (*flag) ew_body<true>(csr_edge, ew1, eb1, ew2, eb2, csr_src, ew4, w1, b1, w2, b2);
    else       ew_body<false>(csr_edge, ew1, eb1, ew2, eb2, csr_src, ew4, w1, b1, w2, b2);
}

// ---------------- layer 0 dense ----------------

template <bool BF>
__device__ __forceinline__ void dense0_body(const void* __restrict__ x,
                                            const void* __restrict__ W,
                                            const void* __restrict__ b,
                                            unsigned short* __restrict__ h,
                                            float* Wl, float (*xl)[32]) {
    int t = threadIdx.x, w = t >> 6, lane = t & 63;
    for (int i = t; i < 32 * 64; i += 256) Wl[i] = LD<BF>(W, i);
    int v0 = blockIdx.x * 16 + w * 4;
    if (lane < 32) {
        #pragma unroll
        for (int n = 0; n < 4; n++)
            xl[w * 4 + n][lane] = LD<BF>(x, (size_t)(v0 + n) * 32 + lane);
    }
    __syncthreads();
    float bias = LD<BF>(b, lane);
    float a0 = bias, a1 = bias, a2 = bias, a3 = bias;
    #pragma unroll 8
    for (int k = 0; k < 32; k++) {
        float wv = Wl[k * 64 + lane];
        a0 = fmaf(xl[w * 4 + 0][k], wv, a0);
        a1 = fmaf(xl[w * 4 + 1][k], wv, a1);
        a2 = fmaf(xl[w * 4 + 2][k], wv, a2);
        a3 = fmaf(xl[w * 4 + 3][k], wv, a3);
    }
    h[(size_t)(v0 + 0) * 64 + lane] = f2bf(a0);
    h[(size_t)(v0 + 1) * 64 + lane] = f2bf(a1);
    h[(size_t)(v0 + 2) * 64 + lane] = f2bf(a2);
    h[(size_t)(v0 + 3) * 64 + lane] = f2bf(a3);
}

__global__ void k_dense0(const int* __restrict__ flag, const void* x, const void* W,
                         const void* b, unsigned short* h) {
    __shared__ float Wl[32 * 64];
    __shared__ float xl[16][32];
    if (*flag) dense0_body<true>(x, W, b, h, Wl, xl);
    else       dense0_body<false>(x, W, b, h, Wl, xl);
}

// ---------------- aggregation: 16 lanes/node, per-lane scalar accumulators --
// h rows = 64 bf16 = 16 uint2. Group of 16 lanes owns one node; lane j owns
// channel quad 4j..4j+3 (one uint2 = 8B gather; group reads 128B/row
// contiguous). Accumulators are scalars held per-lane across all edges ->
// no butterfly, no shfl. idx/ew loads: all 16 lanes of a group read the
// same address (HW broadcast, L1-resident sequential stream). 2 edges per
// iteration, depth-1 scalar prefetch. No unions/arrays (scratch-safe).

__device__ __forceinline__ float4 agg16(int p, int d,
                                        const int* __restrict__ csr_src,
                                        const float* __restrict__ ew,
                                        const uint2* __restrict__ hu2,
                                        int j) {
    float a0 = 0.f, a1 = 0.f, a2 = 0.f, a3 = 0.f;
    int i0 = 0, i1 = 0;
    float e0 = 0.f, e1 = 0.f;
    if (d > 0) { i0 = csr_src[p]; e0 = ew[p]; }
    if (d > 1) { i1 = csr_src[p + 1]; e1 = ew[p + 1]; }
    int rem = d;
    while (rem > 0) {
        int n0 = 0, n1 = 0;
        float f0 = 0.f, f1 = 0.f;
        if (rem > 2) { n0 = csr_src[p + 2]; f0 = ew[p + 2]; }
        if (rem > 3) { n1 = csr_src[p + 3]; f1 = ew[p + 3]; }
        uint2 g0 = hu2[(size_t)i0 * 16 + j];
        uint2 g1 = hu2[(size_t)i1 * 16 + j];   // rem==1: i1=0,e1=0 -> adds 0
        a0 = fmaf(e0, __uint_as_float(g0.x << 16), a0);
        a1 = fmaf(e0, __uint_as_float(g0.x & 0xffff0000u), a1);
        a2 = fmaf(e0, __uint_as_float(g0.y << 16), a2);
        a3 = fmaf(e0, __uint_as_float(g0.y & 0xffff0000u), a3);
        a0 = fmaf(e1, __uint_as_float(g1.x << 16), a0);
        a1 = fmaf(e1, __uint_as_float(g1.x & 0xffff0000u), a1);
        a2 = fmaf(e1, __uint_as_float(g1.y << 16), a2);
        a3 = fmaf(e1, __uint_as_float(g1.y & 0xffff0000u), a3);
        i0 = n0; e0 = f0; i1 = n1; e1 = f1;
        p += 2; rem -= 2;
    }
    return make_float4(fmaxf(a0, 0.f), fmaxf(a1, 0.f), fmaxf(a2, 0.f), fmaxf(a3, 0.f));
}

// ---------------- fused: x = relu(agg(h_in)); h_out = x @ W + b ----------------
// 16 nodes/block (4 waves x 4 groups x 1 node); LDS 20KB

template <bool BF>
__device__ __forceinline__ void fuse_body(const int* row_start, const int* deg,
                                          const int* __restrict__ csr_src,
                                          const float* __restrict__ ew,
                                          const uint2* __restrict__ hu2,
                                          const void* W, int Woff, const void* b, int boff,
                                          unsigned short* h_out,
                                          float* Wl, float (*xs)[64]) {
    int t = threadIdx.x, w = t >> 6, lane = t & 63;
    for (int i = t; i < 64 * 64; i += 256) Wl[i] = LD<BF>(W, Woff + i);

    int g = lane >> 4, j = lane & 15;
    int idx = w * 4 + g;
    int v = blockIdx.x * 16 + idx;   // grid exact: 6250*16 = 100000
    float4 r = agg16(row_start[v], deg[v], csr_src, ew, hu2, j);
    *(float4*)&xs[idx][4 * j] = r;   // relu already applied
    __syncthreads();

    float bias = LD<BF>(b, boff + lane);
    float A0 = bias, A1 = bias, A2 = bias, A3 = bias;
    for (int k = 0; k < 64; k += 4) {
        float w0 = Wl[(k + 0) * 64 + lane];
        float w1 = Wl[(k + 1) * 64 + lane];
        float w2 = Wl[(k + 2) * 64 + lane];
        float w3 = Wl[(k + 3) * 64 + lane];
        float4 x0 = *(const float4*)&xs[w * 4 + 0][k];   // lane-uniform: LDS broadcast
        float4 x1 = *(const float4*)&xs[w * 4 + 1][k];
        float4 x2 = *(const float4*)&xs[w * 4 + 2][k];
        float4 x3 = *(const float4*)&xs[w * 4 + 3][k];
        A0 = fmaf(x0.x, w0, A0); A0 = fmaf(x0.y, w1, A0); A0 = fmaf(x0.z, w2, A0); A0 = fmaf(x0.w, w3, A0);
        A1 = fmaf(x1.x, w0, A1); A1 = fmaf(x1.y, w1, A1); A1 = fmaf(x1.z, w2, A1); A1 = fmaf(x1.w, w3, A1);
        A2 = fmaf(x2.x, w0, A2); A2 = fmaf(x2.y, w1, A2); A2 = fmaf(x2.z, w2, A2); A2 = fmaf(x2.w, w3, A2);
        A3 = fmaf(x3.x, w0, A3); A3 = fmaf(x3.y, w1, A3); A3 = fmaf(x3.z, w2, A3); A3 = fmaf(x3.w, w3, A3);
    }
    int v0 = blockIdx.x * 16 + w * 4;
    h_out[(size_t)(v0 + 0) * 64 + lane] = f2bf(A0);
    h_out[(size_t)(v0 + 1) * 64 + lane] = f2bf(A1);
    h_out[(size_t)(v0 + 2) * 64 + lane] = f2bf(A2);
    h_out[(size_t)(v0 + 3) * 64 + lane] = f2bf(A3);
}

__global__ void k_fuse(const int* __restrict__ flag,
                       const int* row_start, const int* deg,
                       const int* __restrict__ csr_src, const float* __restrict__ ew,
                       const void* hu,
                       const void* W, int Woff, const void* b, int boff,
                       unsigned short* h_out) {
    __shared__ float Wl[64 * 64];
    __shared__ float xs[16][64];
    if (*flag)
        fuse_body<true>(row_start, deg, csr_src, ew, (const uint2*)hu,
                        W, Woff, b, boff, h_out, Wl, xs);
    else
        fuse_body<false>(row_start, deg, csr_src, ew, (const uint2*)hu,
                         W, Woff, b, boff, h_out, Wl, xs);
}

// ---------------- fused final: x3 = relu(agg(h3)); heads -> out ---------------
// 16 nodes/block (4 waves x 4 groups)

template <bool BF>
__device__ __forceinline__ void fuse_heads_body(
        const int* row_start, const int* deg,
        const int* __restrict__ csr_src, const float* __restrict__ ew,
        const uint2* __restrict__ hu2,
        const void* rh1w, const void* rh1b, const void* rh2w, const void* rh2b,
        const void* meanw, const void* meanb, const void* stdw, const void* stdb,
        const void* cls1w, const void* cls1b, const void* cls2w, const void* cls2b,
        void* __restrict__ out,
        float* s_rh1, float* s_cls1, float* s_rh2, float* s_cls2,
        float* s_rh1b, float* s_cls1b, float* s_rh2b, float* s_mw, float* s_sw,
        float* s_c2b, float* s_msb,
        float (*xs)[64], float (*r1)[32], float (*c1h)[32], float (*r2)[16]) {
    int t = threadIdx.x, w = t >> 6, lane = t & 63;
    for (int i = t; i < 2048; i += 256) { s_rh1[i] = LD<BF>(rh1w, i); s_cls1[i] = LD<BF>(cls1w, i); }
    for (int i = t; i < 512; i += 256) s_rh2[i] = LD<BF>(rh2w, i);
    if (t < 64) s_cls2[t] = LD<BF>(cls2w, t);
    if (t < 32) { s_rh1b[t] = LD<BF>(rh1b, t); s_cls1b[t] = LD<BF>(cls1b, t); }
    else if (t < 48) { int i = t - 32; s_rh2b[i] = LD<BF>(rh2b, i); s_mw[i] = LD<BF>(meanw, i); s_sw[i] = LD<BF>(stdw, i); }
    else if (t == 48) { s_msb[0] = LD<BF>(meanb, 0); s_msb[1] = LD<BF>(stdb, 0); }
    else if (t == 49) { s_c2b[0] = LD<BF>(cls2b, 0); s_c2b[1] = LD<BF>(cls2b, 1); }

    int g = lane >> 4, j = lane & 15;
    int idx0 = w * 4 + g;
    int v00 = blockIdx.x * 16;
    float4 r = agg16(row_start[v00 + idx0], deg[v00 + idx0], csr_src, ew, hu2, j);
    *(float4*)&xs[idx0][4 * j] = r;
    __syncthreads();

    #pragma unroll
    for (int n = 0; n < 4; n++) {
        int idx = w * 4 + n;
        int c = lane & 31;
        const float* Wp = (lane < 32) ? s_rh1 : s_cls1;
        float a = (lane < 32) ? s_rh1b[c] : s_cls1b[c];
        #pragma unroll 8
        for (int k = 0; k < 64; k++) a = fmaf(xs[idx][k], Wp[k * 32 + c], a);
        a = fmaxf(a, 0.f);
        if (lane < 32) r1[idx][c] = a; else c1h[idx][c] = a;
    }
    __syncthreads();

    #pragma unroll
    for (int n = 0; n < 4; n++) {
        int idx = w * 4 + n;
        if (lane < 16) {
            float a = s_rh2b[lane];
            #pragma unroll
            for (int k = 0; k < 32; k++) a = fmaf(r1[idx][k], s_rh2[k * 16 + lane], a);
            r2[idx][lane] = fmaxf(a, 0.f);
        }
    }
    __syncthreads();

    #pragma unroll
    for (int n = 0; n < 4; n++) {
        int idx = w * 4 + n;
        int v = v00 + idx;
        if (lane == 0) {
            float m = s_msb[0];
            #pragma unroll
            for (int k = 0; k < 16; k++) m = fmaf(r2[idx][k], s_mw[k], m);
            if (BF) ((unsigned short*)out)[v] = f2bf(m); else ((float*)out)[v] = m;
        } else if (lane == 1) {
            float sv = s_msb[1];
            #pragma unroll
            for (int k = 0; k < 16; k++) sv = fmaf(r2[idx][k], s_sw[k], sv);
            float sp = fmaxf(sv, 0.f) + log1pf(expf(-fabsf(sv)));   // stable softplus
            if (BF) ((unsigned short*)out)[N_NODES + v] = f2bf(sp); else ((float*)out)[N_NODES + v] = sp;
        } else if (lane < 4) {
            int jj = lane - 2;
            float a = s_c2b[jj];
            #pragma unroll
            for (int k = 0; k < 32; k++) a = fmaf(c1h[idx][k], s_cls2[k * 2 + jj], a);
            size_t pos = (size_t)2 * N_NODES + (size_t)v * 2 + jj;
            if (BF) ((unsigned short*)out)[pos] = f2bf(a); else ((float*)out)[pos] = a;
        }
    }
}

__global__ void k_fuse_heads(const int* __restrict__ flag,
                             const int* row_start, const int* deg,
                             const int* __restrict__ csr_src, const float* __restrict__ ew,
                             const void* hu,
                             const void* rh1w, const void* rh1b, const void* rh2w, const void* rh2b,
                             const void* meanw, const void* meanb, const void* stdw, const void* stdb,
                             const void* cls1w, const void* cls1b, const void* cls2w, const void* cls2b,
                             void* out) {
    __shared__ float s_rh1[64 * 32], s_cls1[64 * 32], s_rh2[32 * 16], s_cls2[32 * 2];
    __shared__ float s_rh1b[32], s_cls1b[32], s_rh2b[16], s_mw[16], s_sw[16], s_c2b[2], s_msb[2];
    __shared__ float xs[16][64], r1[16][32], c1h[16][32], r2[16][16];
    if (*flag)
        fuse_heads_body<true>(row_start, deg, csr_src, ew, (const uint2*)hu,
                              rh1w, rh1b, rh2w, rh2b, meanw, meanb, stdw, stdb,
                              cls1w, cls1b, cls2w, cls2b, out,
                              s_rh1, s_cls1, s_rh2, s_cls2, s_rh1b, s_cls1b, s_rh2b,
                              s_mw, s_sw, s_c2b, s_msb, xs, r1, c1h, r2);
    else
        fuse_heads_body<false>(row_start, deg, csr_src, ew, (const uint2*)hu,
                               rh1w, rh1b, rh2w, rh2b, meanw, meanb, stdw, stdb,
                               cls1w, cls1b, cls2w, cls2b, out,
                               s_rh1, s_cls1, s_rh2, s_cls2, s_rh1b, s_cls1b, s_rh2b,
                               s_mw, s_sw, s_c2b, s_msb, xs, r1, c1h, r2);
}

// ---------------- launch ----------------

extern "C" void kernel_launch(void* const* d_in, const int* in_sizes, int n_in,
                              void* d_out, int out_size, void* d_ws, size_t ws_size,
                              hipStream_t stream) {
    const void* x_in  = d_in[0];
    const int* ei     = (const int*)d_in[1];
    const void* ea    = d_in[2];
    const void* W0    = d_in[3];
    const void* b0    = d_in[4];
    const void* Ws    = d_in[5];
    const void* bs    = d_in[6];
    const void* ew1   = d_in[7];
    const void* eb1   = d_in[8];
    const void* ew2   = d_in[9];
    const void* eb2   = d_in[10];
    const void* rh1w  = d_in[11];
    const void* rh1b  = d_in[12];
    const void* rh2w  = d_in[13];
    const void* rh2b  = d_in[14];
    const void* meanw = d_in[15];
    const void* meanb = d_in[16];
    const void* stdw  = d_in[17];
    const void* stdb  = d_in[18];
    const void* cls1w = d_in[19];
    const void* cls1b = d_in[20];
    const void* cls2w = d_in[21];
    const void* cls2b = d_in[22];

    char* wsp = (char*)d_ws;
    auto alloc = [&](size_t bytes) -> char* {
        char* p = wsp;
        wsp += (bytes + 255) & ~(size_t)255;
        return p;
    };
    // footprint ~59 MB (< 78.2 MB proven):
    //   csr_edge (25.6 MB) is dead after k_ew -> aliased with hA+hB (12.8+12.8)
    int* flag       = (int*)alloc(4);
    int* deg        = (int*)alloc((size_t)N_NODES * 4);
    int* row_start  = (int*)alloc((size_t)N_NODES * 4);
    int* cursor     = (int*)alloc((size_t)N_NODES * 4);
    int* bsum       = (int*)alloc((size_t)NB_SCAN * 4);
    int* boff       = (int*)alloc((size_t)NB_SCAN * 4);
    int* csr_src    = (int*)alloc((size_t)N_EDGES * 4);
    float* ew4      = (float*)alloc((size_t)4 * N_EDGES * 4);
    char* hreg      = alloc((size_t)N_EDGES * 16);       // union region, 25.6 MB
    uint4* csr_edge = (uint4*)hreg;
    unsigned short* hA = (unsigned short*)hreg;
    unsigned short* hB = (unsigned short*)(hreg + (size_t)N_NODES * 64 * 2);

    k_detect<<<1, 256, 0, stream>>>((const unsigned*)x_in, flag);
    hipMemsetAsync(deg, 0, (size_t)N_NODES * 4, stream);
    k_hist<<<6250, 256, 0, stream>>>(ei, deg);
    k_scan_partial<<<NB_SCAN, 256, 0, stream>>>(deg, bsum);
    k_scan_mid<<<1, 512, 0, stream>>>(bsum, boff);
    k_scan_final<<<NB_SCAN, 256, 0, stream>>>(deg, boff, row_start, cursor);
    k_scatter<<<6250, 256, 0, stream>>>(flag, ei, ea, cursor, csr_edge);
    k_ew<<<6250, 256, 0, stream>>>(flag, csr_edge, ew1, eb1, ew2, eb2, csr_src, ew4);

    // h0 = x_in @ W0 + b0   (hA clobbers csr_edge region -- dead after k_ew)
    k_dense0<<<6250, 256, 0, stream>>>(flag, x_in, W0, b0, hA);

    unsigned short* hin = hA;
    unsigned short* hout = hB;
    for (int l = 0; l < 3; l++) {
        k_fuse<<<6250, 256, 0, stream>>>(flag, row_start, deg, csr_src,
                                         ew4 + (size_t)l * N_EDGES, hin,
                                         Ws, l * 64 * 64, bs, l * 64, hout);
        unsigned short* tmp = hin; hin = hout; hout = tmp;
    }
    k_fuse_heads<<<6250, 256, 0, stream>>>(flag, row_start, deg, csr_src,
                                           ew4 + (size_t)3 * N_EDGES, hin,
                                           rh1w, rh1b, rh2w, rh2b, meanw, meanb,
                                           stdw, stdb, cls1w, cls1b, cls2w, cls2b,
                                           d_out);
}